// Round 8
// baseline (244.070 us; speedup 1.0000x reference)
//
#include <hip/hip_runtime.h>
#include <hip/hip_bf16.h>
#include <stdint.h>

#define N_OUT 512
#define N_IN 64
#define D_TOT 576               // N_IN + N_OUT
#define BM 32                   // batch rows per block
#define ROW_BYTES (D_TOT * 2)   // 1152 bytes per LDS row (bf16)
#define NWAVES 4                // 256 threads per block

typedef __attribute__((ext_vector_type(8))) short short8_t;   // 8 x bf16
typedef __attribute__((ext_vector_type(4))) float f32x4;
typedef unsigned short u16;

// HW bf16 conversion (RNE)
__device__ __forceinline__ u16 f2bf(float f) {
    __hip_bfloat16 h = __float2bfloat16(f);
    return *reinterpret_cast<u16*>(&h);
}
__device__ __forceinline__ float bf2f(u16 u) {
    union { uint32_t u; float f; } v;
    v.u = ((uint32_t)u) << 16;
    return v.f;
}

// Prep: masked bf16 weights, k-major fragment layout:
//   dst[((kk*4 + lg) * 512 + col) * 8 + j]  holds W[col][kk*32 + lg*8 + j]
// so a wave's B-fragment load (16 cols x 16B) is 4 contiguous 256B segments.
__global__ void prep_weights_kernel(const float* __restrict__ PA,
                                    const float* __restrict__ PB,
                                    u16* __restrict__ WA,
                                    u16* __restrict__ WB) {
    const int col = blockIdx.x;          // output index i in [0,512)
    const int lim = N_IN + col;          // valid k < lim
    const float* pa = PA + (size_t)col * D_TOT;
    const float* pb = PB + (size_t)col * D_TOT;
    for (int k = threadIdx.x; k < D_TOT; k += blockDim.x) {
        int kk = k >> 5, lg = (k >> 3) & 3, j = k & 7;
        size_t dst = ((size_t)(kk * 4 + lg) * N_OUT + col) * 8 + j;
        bool valid = (k < lim);
        WA[dst] = valid ? f2bf(pa[k]) : (u16)0;
        WB[dst] = valid ? f2bf(pb[k]) : (u16)0;
    }
}

// Compile-time-trip-count K-loop for one 32-col group (KS = 3+g ksteps).
// Full unroll + 1-deep b-fragment prefetch: independent weight loads issue
// ahead of the MFMAs instead of a per-iteration vmcnt drain (R7 diagnosis).
template<int KS>
__device__ __forceinline__ void run_group(const char* xt,
                                          const u16* __restrict__ WA,
                                          const u16* __restrict__ WB,
                                          int c0, int lr, int lg,
                                          f32x4 accA[2][2], f32x4 accB[2][2]) {
    #pragma unroll
    for (int m = 0; m < 2; ++m)
        #pragma unroll
        for (int n = 0; n < 2; ++n) {
            accA[m][n] = (f32x4)(0.0f);
            accB[m][n] = (f32x4)(0.0f);
        }

    // per-lane element base: (lg*512 + c0 + lr)*8 ; kstep stride = 4*512*8 = 16384
    const u16* wa0 = WA + ((size_t)lg * N_OUT + c0 + lr) * 8;
    const u16* wb0 = WB + ((size_t)lg * N_OUT + c0 + lr) * 8;

    short8_t ba[2], bb[2];
    #pragma unroll
    for (int n = 0; n < 2; ++n) {
        ba[n] = *(const short8_t*)(wa0 + n * 128);
        bb[n] = *(const short8_t*)(wb0 + n * 128);
    }

    #pragma unroll
    for (int kk = 0; kk < KS; ++kk) {
        // A-fragments from LDS (swizzled)
        short8_t a[2];
        const int kb = kk * 64 + lg * 16;
        #pragma unroll
        for (int m = 0; m < 2; ++m) {
            int row = (m << 4) + lr;
            int addr = (row * ROW_BYTES + kb) ^ ((row & 7) << 4);
            a[m] = *(const short8_t*)(xt + addr);
        }
        // prefetch next kstep's weight fragments before this kstep's MFMAs
        short8_t nba[2], nbb[2];
        if (kk + 1 < KS) {
            const u16* wa1 = wa0 + (size_t)(kk + 1) * 16384;
            const u16* wb1 = wb0 + (size_t)(kk + 1) * 16384;
            #pragma unroll
            for (int n = 0; n < 2; ++n) {
                nba[n] = *(const short8_t*)(wa1 + n * 128);
                nbb[n] = *(const short8_t*)(wb1 + n * 128);
            }
        }
        #pragma unroll
        for (int m = 0; m < 2; ++m) {
            #pragma unroll
            for (int n = 0; n < 2; ++n) {
                accA[m][n] = __builtin_amdgcn_mfma_f32_16x16x32_bf16(a[m], ba[n], accA[m][n], 0, 0, 0);
                accB[m][n] = __builtin_amdgcn_mfma_f32_16x16x32_bf16(a[m], bb[n], accB[m][n], 0, 0, 0);
            }
        }
        if (kk + 1 < KS) {
            #pragma unroll
            for (int n = 0; n < 2; ++n) { ba[n] = nba[n]; bb[n] = nbb[n]; }
        }
    }
}

// Main fused kernel — R6 config (256 thr, BM=32, 4 groups/wave, 37.4 KB LDS);
// only the K-loop codegen changed (templated trip count + prefetch).
__global__ __launch_bounds__(256)
void maf_main_kernel(const float* __restrict__ X,
                     const float* __restrict__ Cc,
                     const u16* __restrict__ WA,
                     const u16* __restrict__ WB,
                     float* __restrict__ Z,
                     float* __restrict__ LD) {
    extern __shared__ char smem[];
    char* xt = smem;                                   // [32][1152] bytes, swizzled
    float* ldsum = (float*)(smem + BM * ROW_BYTES);    // [4][32]

    const int tid = threadIdx.x;
    const int r0 = blockIdx.x * BM;

    // ---- stage c (k in [0,64)) : 256 chunks of 8 f32, 1 per thread ----
    {
        int row = tid >> 3, cc = tid & 7;
        const float* src = Cc + (size_t)(r0 + row) * N_IN + cc * 8;
        f32x4 v0 = *(const f32x4*)src;
        f32x4 v1 = *(const f32x4*)(src + 4);
        short8_t p;
        p[0] = (short)f2bf(v0[0]); p[1] = (short)f2bf(v0[1]);
        p[2] = (short)f2bf(v0[2]); p[3] = (short)f2bf(v0[3]);
        p[4] = (short)f2bf(v1[0]); p[5] = (short)f2bf(v1[1]);
        p[6] = (short)f2bf(v1[2]); p[7] = (short)f2bf(v1[3]);
        int addr = (row * ROW_BYTES + cc * 16) ^ ((row & 7) << 4);
        *(short8_t*)(xt + addr) = p;
    }
    // ---- stage X (k in [64,576)) : 2048 chunks, 8 per thread ----
    #pragma unroll
    for (int i = 0; i < 8; ++i) {
        int id = tid + i * 256;
        int row = id >> 6, xc = id & 63;
        const float* src = X + (size_t)(r0 + row) * N_OUT + xc * 8;
        f32x4 v0 = *(const f32x4*)src;
        f32x4 v1 = *(const f32x4*)(src + 4);
        short8_t p;
        p[0] = (short)f2bf(v0[0]); p[1] = (short)f2bf(v0[1]);
        p[2] = (short)f2bf(v0[2]); p[3] = (short)f2bf(v0[3]);
        p[4] = (short)f2bf(v1[0]); p[5] = (short)f2bf(v1[1]);
        p[6] = (short)f2bf(v1[2]); p[7] = (short)f2bf(v1[3]);
        int addr = (row * ROW_BYTES + (8 + xc) * 16) ^ ((row & 7) << 4);
        *(short8_t*)(xt + addr) = p;
    }
    __syncthreads();

    const int wid = tid >> 6;
    const int lane = tid & 63;
    const int lr = lane & 15;   // fragment row (A) / col (B,C)
    const int lg = lane >> 4;   // k sub-block (A,B) / row quad (C)

    float part[2][4];           // per-lane log_det partials [m][j]
    #pragma unroll
    for (int m = 0; m < 2; ++m)
        #pragma unroll
        for (int j = 0; j < 4; ++j) part[m][j] = 0.0f;

    const int groups[4] = { wid, 7 - wid, 8 + wid, 15 - wid };  // 42 ksteps total

    #pragma unroll
    for (int gi = 0; gi < 4; ++gi) {
        const int g = groups[gi];
        const int c0 = g << 5;          // first column of group

        f32x4 accA[2][2], accB[2][2];
        // wave-uniform dispatch on compile-time trip count (KS = 3+g)
        switch (g) {
            case 0:  run_group<3>(xt, WA, WB, c0, lr, lg, accA, accB); break;
            case 1:  run_group<4>(xt, WA, WB, c0, lr, lg, accA, accB); break;
            case 2:  run_group<5>(xt, WA, WB, c0, lr, lg, accA, accB); break;
            case 3:  run_group<6>(xt, WA, WB, c0, lr, lg, accA, accB); break;
            case 4:  run_group<7>(xt, WA, WB, c0, lr, lg, accA, accB); break;
            case 5:  run_group<8>(xt, WA, WB, c0, lr, lg, accA, accB); break;
            case 6:  run_group<9>(xt, WA, WB, c0, lr, lg, accA, accB); break;
            case 7:  run_group<10>(xt, WA, WB, c0, lr, lg, accA, accB); break;
            case 8:  run_group<11>(xt, WA, WB, c0, lr, lg, accA, accB); break;
            case 9:  run_group<12>(xt, WA, WB, c0, lr, lg, accA, accB); break;
            case 10: run_group<13>(xt, WA, WB, c0, lr, lg, accA, accB); break;
            case 11: run_group<14>(xt, WA, WB, c0, lr, lg, accA, accB); break;
            case 12: run_group<15>(xt, WA, WB, c0, lr, lg, accA, accB); break;
            case 13: run_group<16>(xt, WA, WB, c0, lr, lg, accA, accB); break;
            case 14: run_group<17>(xt, WA, WB, c0, lr, lg, accA, accB); break;
            default: run_group<18>(xt, WA, WB, c0, lr, lg, accA, accB); break;
        }

        // ---- epilogue for this 32-col group ----
        // C/D layout (verified m89/m91): col = lane&15, row = (lane>>4)*4 + reg
        #pragma unroll
        for (int m = 0; m < 2; ++m) {
            #pragma unroll
            for (int n = 0; n < 2; ++n) {
                int col = c0 + (n << 4) + lr;
                #pragma unroll
                for (int j = 0; j < 4; ++j) {
                    int row = (m << 4) + (lg << 2) + j;
                    float Av = accA[m][n][j];
                    float Bv = accB[m][n][j];
                    int xaddr = (row * ROW_BYTES + (N_IN + col) * 2) ^ ((row & 7) << 4);
                    float Xf = bf2f(*(const u16*)(xt + xaddr));
                    Z[(size_t)(r0 + row) * N_OUT + col] = Xf * __expf(Av) + Bv;
                    part[m][j] += Av;
                }
            }
        }
    }

    // ---- log_det: reduce across the 16 lanes that share rows (same lg) ----
    #pragma unroll
    for (int m = 0; m < 2; ++m) {
        #pragma unroll
        for (int j = 0; j < 4; ++j) {
            float v = part[m][j];
            v += __shfl_xor(v, 1);
            v += __shfl_xor(v, 2);
            v += __shfl_xor(v, 4);
            v += __shfl_xor(v, 8);
            if (lr == 0) ldsum[(wid << 5) + (m << 4) + (lg << 2) + j] = v;
        }
    }
    __syncthreads();
    if (tid < BM) {
        float s = 0.0f;
        #pragma unroll
        for (int w = 0; w < NWAVES; ++w) s += ldsum[(w << 5) + tid];
        LD[(size_t)r0 + tid] = s;
    }
}

extern "C" void kernel_launch(void* const* d_in, const int* in_sizes, int n_in,
                              void* d_out, int out_size, void* d_ws, size_t ws_size,
                              hipStream_t stream) {
    const float* X  = (const float*)d_in[0];
    const float* Cc = (const float*)d_in[1];
    const float* PA = (const float*)d_in[2];
    const float* PB = (const float*)d_in[3];

    u16* WA = (u16*)d_ws;                          // 512*576*2 bytes (k-major)
    u16* WB = WA + (size_t)N_OUT * D_TOT;          // another 512*576*2

    float* Z  = (float*)d_out;
    const size_t batch = (size_t)in_sizes[0] / N_OUT;   // 131072
    float* LD = Z + batch * N_OUT;

    prep_weights_kernel<<<N_OUT, 256, 0, stream>>>(PA, PB, WA, WB);

    const size_t lds_bytes = (size_t)BM * ROW_BYTES + NWAVES * BM * sizeof(float); // 37376
    const int grid = (int)(batch / BM);            // 4096
    maf_main_kernel<<<grid, 256, lds_bytes, stream>>>(X, Cc, WA, WB, Z, LD);
}

// Round 9
// 216.360 us; speedup vs baseline: 1.1281x; 1.1281x over previous
//
#include <hip/hip_runtime.h>
#include <hip/hip_bf16.h>
#include <stdint.h>

#define N_OUT 512
#define N_IN 64
#define D_TOT 576               // N_IN + N_OUT
#define BM 32                   // batch rows per block
#define ROW_BYTES (D_TOT * 2)   // 1152 bytes per LDS row (bf16)
#define NWAVES 4                // 256 threads per block

typedef __attribute__((ext_vector_type(8))) short short8_t;   // 8 x bf16
typedef __attribute__((ext_vector_type(4))) float f32x4;
typedef unsigned short u16;

// HW bf16 conversion (RNE)
__device__ __forceinline__ u16 f2bf(float f) {
    __hip_bfloat16 h = __float2bfloat16(f);
    return *reinterpret_cast<u16*>(&h);
}
__device__ __forceinline__ float bf2f(u16 u) {
    union { uint32_t u; float f; } v;
    v.u = ((uint32_t)u) << 16;
    return v.f;
}

// Prep: masked bf16 weights, k-major fragment layout:
//   dst[((kk*4 + lg) * 512 + col) * 8 + j]  holds W[col][kk*32 + lg*8 + j]
// so a wave's B-fragment load (16 cols x 16B) is 4 contiguous 256B segments.
__global__ void prep_weights_kernel(const float* __restrict__ PA,
                                    const float* __restrict__ PB,
                                    u16* __restrict__ WA,
                                    u16* __restrict__ WB) {
    const int col = blockIdx.x;          // output index i in [0,512)
    const int lim = N_IN + col;          // valid k < lim
    const float* pa = PA + (size_t)col * D_TOT;
    const float* pb = PB + (size_t)col * D_TOT;
    for (int k = threadIdx.x; k < D_TOT; k += blockDim.x) {
        int kk = k >> 5, lg = (k >> 3) & 3, j = k & 7;
        size_t dst = ((size_t)(kk * 4 + lg) * N_OUT + col) * 8 + j;
        bool valid = (k < lim);
        WA[dst] = valid ? f2bf(pa[k]) : (u16)0;
        WB[dst] = valid ? f2bf(pb[k]) : (u16)0;
    }
}

// Main fused kernel — R6 structure (best: 212 us) with ONE change:
// X/c staging loads and Z stores are NON-TEMPORAL. X streams 33 MB/XCD
// through a 4 MB L2 per launch and was evicting the 1.18 MB weight set,
// forcing the K-loop's weight loads to L3/HBM latency (~500-900 cyc) that
// 2.5 waves/SIMD cannot hide. nt hints keep weights L2-resident.
__global__ __launch_bounds__(256)
void maf_main_kernel(const float* __restrict__ X,
                     const float* __restrict__ Cc,
                     const u16* __restrict__ WA,
                     const u16* __restrict__ WB,
                     float* __restrict__ Z,
                     float* __restrict__ LD) {
    extern __shared__ char smem[];
    char* xt = smem;                                   // [32][1152] bytes, swizzled
    float* ldsum = (float*)(smem + BM * ROW_BYTES);    // [4][32]

    const int tid = threadIdx.x;
    const int r0 = blockIdx.x * BM;

    // ---- stage c (k in [0,64)) : 256 chunks of 8 f32, 1 per thread ----
    {
        int row = tid >> 3, cc = tid & 7;
        const float* src = Cc + (size_t)(r0 + row) * N_IN + cc * 8;
        f32x4 v0 = __builtin_nontemporal_load((const f32x4*)src);
        f32x4 v1 = __builtin_nontemporal_load((const f32x4*)(src + 4));
        short8_t p;
        p[0] = (short)f2bf(v0[0]); p[1] = (short)f2bf(v0[1]);
        p[2] = (short)f2bf(v0[2]); p[3] = (short)f2bf(v0[3]);
        p[4] = (short)f2bf(v1[0]); p[5] = (short)f2bf(v1[1]);
        p[6] = (short)f2bf(v1[2]); p[7] = (short)f2bf(v1[3]);
        int addr = (row * ROW_BYTES + cc * 16) ^ ((row & 7) << 4);
        *(short8_t*)(xt + addr) = p;
    }
    // ---- stage X (k in [64,576)) : 2048 chunks, 8 per thread ----
    #pragma unroll
    for (int i = 0; i < 8; ++i) {
        int id = tid + i * 256;
        int row = id >> 6, xc = id & 63;
        const float* src = X + (size_t)(r0 + row) * N_OUT + xc * 8;
        f32x4 v0 = __builtin_nontemporal_load((const f32x4*)src);
        f32x4 v1 = __builtin_nontemporal_load((const f32x4*)(src + 4));
        short8_t p;
        p[0] = (short)f2bf(v0[0]); p[1] = (short)f2bf(v0[1]);
        p[2] = (short)f2bf(v0[2]); p[3] = (short)f2bf(v0[3]);
        p[4] = (short)f2bf(v1[0]); p[5] = (short)f2bf(v1[1]);
        p[6] = (short)f2bf(v1[2]); p[7] = (short)f2bf(v1[3]);
        int addr = (row * ROW_BYTES + (8 + xc) * 16) ^ ((row & 7) << 4);
        *(short8_t*)(xt + addr) = p;
    }
    __syncthreads();

    const int wid = tid >> 6;
    const int lane = tid & 63;
    const int lr = lane & 15;   // fragment row (A) / col (B,C)
    const int lg = lane >> 4;   // k sub-block (A,B) / row quad (C)

    float part[2][4];           // per-lane log_det partials [m][j]
    #pragma unroll
    for (int m = 0; m < 2; ++m)
        #pragma unroll
        for (int j = 0; j < 4; ++j) part[m][j] = 0.0f;

    const int groups[4] = { wid, 7 - wid, 8 + wid, 15 - wid };  // 42 ksteps total

    #pragma unroll
    for (int gi = 0; gi < 4; ++gi) {
        const int g = groups[gi];
        const int c0 = g << 5;          // first column of group
        const int ksteps = 3 + g;       // causal mask: k < 64 + col

        f32x4 accA[2][2], accB[2][2];
        #pragma unroll
        for (int m = 0; m < 2; ++m)
            #pragma unroll
            for (int n = 0; n < 2; ++n) {
                accA[m][n] = (f32x4)(0.0f);
                accB[m][n] = (f32x4)(0.0f);
            }

        #pragma unroll 3
        for (int kk = 0; kk < ksteps; ++kk) {
            const int kb = kk * 64 + lg * 16;   // byte offset of this lane's k-slice
            short8_t a[2];
            #pragma unroll
            for (int m = 0; m < 2; ++m) {
                int row = (m << 4) + lr;
                int addr = (row * ROW_BYTES + kb) ^ ((row & 7) << 4);
                a[m] = *(const short8_t*)(xt + addr);
            }
            short8_t ba[2], bb[2];
            const size_t wbase = (size_t)((kk << 2) + lg) * N_OUT + c0 + lr;
            #pragma unroll
            for (int n = 0; n < 2; ++n) {
                size_t off = (wbase + (n << 4)) * 8;
                ba[n] = *(const short8_t*)(WA + off);
                bb[n] = *(const short8_t*)(WB + off);
            }
            #pragma unroll
            for (int m = 0; m < 2; ++m) {
                #pragma unroll
                for (int n = 0; n < 2; ++n) {
                    accA[m][n] = __builtin_amdgcn_mfma_f32_16x16x32_bf16(a[m], ba[n], accA[m][n], 0, 0, 0);
                    accB[m][n] = __builtin_amdgcn_mfma_f32_16x16x32_bf16(a[m], bb[n], accB[m][n], 0, 0, 0);
                }
            }
        }

        // ---- epilogue for this 32-col group ----
        // C/D layout (verified m89/m91): col = lane&15, row = (lane>>4)*4 + reg
        #pragma unroll
        for (int m = 0; m < 2; ++m) {
            #pragma unroll
            for (int n = 0; n < 2; ++n) {
                int col = c0 + (n << 4) + lr;
                #pragma unroll
                for (int j = 0; j < 4; ++j) {
                    int row = (m << 4) + (lg << 2) + j;
                    float Av = accA[m][n][j];
                    float Bv = accB[m][n][j];
                    int xaddr = (row * ROW_BYTES + (N_IN + col) * 2) ^ ((row & 7) << 4);
                    float Xf = bf2f(*(const u16*)(xt + xaddr));
                    float zv = Xf * __expf(Av) + Bv;
                    __builtin_nontemporal_store(zv, &Z[(size_t)(r0 + row) * N_OUT + col]);
                    part[m][j] += Av;
                }
            }
        }
    }

    // ---- log_det: reduce across the 16 lanes that share rows (same lg) ----
    #pragma unroll
    for (int m = 0; m < 2; ++m) {
        #pragma unroll
        for (int j = 0; j < 4; ++j) {
            float v = part[m][j];
            v += __shfl_xor(v, 1);
            v += __shfl_xor(v, 2);
            v += __shfl_xor(v, 4);
            v += __shfl_xor(v, 8);
            if (lr == 0) ldsum[(wid << 5) + (m << 4) + (lg << 2) + j] = v;
        }
    }
    __syncthreads();
    if (tid < BM) {
        float s = 0.0f;
        #pragma unroll
        for (int w = 0; w < NWAVES; ++w) s += ldsum[(w << 5) + tid];
        LD[(size_t)r0 + tid] = s;
    }
}

extern "C" void kernel_launch(void* const* d_in, const int* in_sizes, int n_in,
                              void* d_out, int out_size, void* d_ws, size_t ws_size,
                              hipStream_t stream) {
    const float* X  = (const float*)d_in[0];
    const float* Cc = (const float*)d_in[1];
    const float* PA = (const float*)d_in[2];
    const float* PB = (const float*)d_in[3];

    u16* WA = (u16*)d_ws;                          // 512*576*2 bytes (k-major)
    u16* WB = WA + (size_t)N_OUT * D_TOT;          // another 512*576*2

    float* Z  = (float*)d_out;
    const size_t batch = (size_t)in_sizes[0] / N_OUT;   // 131072
    float* LD = Z + batch * N_OUT;

    prep_weights_kernel<<<N_OUT, 256, 0, stream>>>(PA, PB, WA, WB);

    const size_t lds_bytes = (size_t)BM * ROW_BYTES + NWAVES * BM * sizeof(float); // 37376
    const int grid = (int)(batch / BM);            // 4096
    maf_main_kernel<<<grid, 256, lds_bytes, stream>>>(X, Cc, WA, WB, Z, LD);
}